// Round 9
// baseline (195.438 us; speedup 1.0000x reference)
//
#include <hip/hip_runtime.h>
#include <hip/hip_bf16.h>

typedef __attribute__((ext_vector_type(8))) short short8;
typedef __attribute__((ext_vector_type(4))) float f32x4;
typedef __attribute__((ext_vector_type(4))) unsigned int u32x4;
typedef unsigned short u16;
typedef unsigned int u32;

typedef u32 __attribute__((address_space(1))) as1_u32;
typedef u32 __attribute__((address_space(3))) as3_u32;

#define NB 4
#define SEQ 2048
#define CH 1024
#define NH 16
#define HD 64
#define M_TOT (NB*SEQ)   // 8192
#define N_TOT (3*CH)     // 3072
#define K_TOT CH         // 1024
#define SCL 0.18033688f  // log2(e) / sqrt(64)

#define MFMA16(a,b,c) __builtin_amdgcn_mfma_f32_16x16x32_bf16((a),(b),(c),0,0,0)

__device__ __forceinline__ u16 f2bf(float f) {
    union { float f; u32 u; } v; v.f = f;
    u32 u = v.u;
    return (u16)((u + 0x7fffu + ((u >> 16) & 1u)) >> 16);
}

__device__ __forceinline__ u32 pkbf2(float a, float b) {
    union { __hip_bfloat162 h; u32 u; } x;
    x.h = __float22bfloat162_rn(float2{a, b});
    return x.u;   // low 16 bits = a, high = b
}

// ---------------- fp32 -> bf16 conversion (x and w in one launch) ----------------
__global__ void cvt_bf16_kernel(const float* __restrict__ x, u16* __restrict__ xb, int nx8,
                                const float* __restrict__ w, u16* __restrict__ wb, int nw8) {
    int i = blockIdx.x * 256 + threadIdx.x;
    const float* src; u16* dst; int idx;
    if (i < nx8) { src = x; dst = xb; idx = i; }
    else { idx = i - nx8; if (idx >= nw8) return; src = w; dst = wb; }
    const float4* s4 = (const float4*)src;
    float4 a = s4[2*idx], b = s4[2*idx+1];
    u32x4 r;
    r[0] = pkbf2(a.x, a.y); r[1] = pkbf2(a.z, a.w);
    r[2] = pkbf2(b.x, b.y); r[3] = pkbf2(b.z, b.w);
    *(u32x4*)(dst + (size_t)idx*8) = r;
}

// ---------------- QKV projection GEMM (unchanged, ~880 TF) ----------------
__global__ __launch_bounds__(256) void qkv_gemm_kernel(
        const u16* __restrict__ A, const u16* __restrict__ W,
        const float* __restrict__ bias,
        u16* __restrict__ qw, u16* __restrict__ kw, u16* __restrict__ vtw)
{
    __shared__ u16 As[128*32];
    __shared__ u16 Bs[128*32];
    const int t = threadIdx.x;
    const int wave = t >> 6;
    const int lane = t & 63;
    const int l15 = lane & 15, lhi = lane >> 4;
    const int wr = wave >> 1, wc = wave & 1;
    const int xcd = blockIdx.x & 7;
    const int idx = blockIdx.x >> 3;
    const int bm = xcd * 8 + (idx & 7);
    const int bn = idx >> 3;

    f32x4 acc[4][4] = {};

    const int arow = t >> 2;
    const int acol = (t & 3) * 8;
    const u16* gA = A + (size_t)(bm*128 + arow)*K_TOT + acol;
    const u16* gB = W + (size_t)(bn*128 + arow)*K_TOT + acol;

    for (int k0 = 0; k0 < K_TOT; k0 += 32) {
        #pragma unroll
        for (int i = 0; i < 2; ++i) {
            __builtin_amdgcn_global_load_lds(
                (const as1_u32*)(gA + (size_t)i*64*K_TOT + k0),
                (as3_u32*)(As + i*2048 + wave*512), 16, 0, 0);
            __builtin_amdgcn_global_load_lds(
                (const as1_u32*)(gB + (size_t)i*64*K_TOT + k0),
                (as3_u32*)(Bs + i*2048 + wave*512), 16, 0, 0);
        }
        __syncthreads();
        short8 af[4], bfr[4];
        #pragma unroll
        for (int m = 0; m < 4; ++m)
            af[m] = *(const short8*)(As + (wr*64 + m*16 + l15)*32 + lhi*8);
        #pragma unroll
        for (int n = 0; n < 4; ++n)
            bfr[n] = *(const short8*)(Bs + (wc*64 + n*16 + l15)*32 + lhi*8);
        #pragma unroll
        for (int m = 0; m < 4; ++m)
            #pragma unroll
            for (int n = 0; n < 4; ++n)
                acc[m][n] = MFMA16(af[m], bfr[n], acc[m][n]);
        __syncthreads();
    }

    const int colbase = bn*128 + wc*64;
    const int which = colbase >> 10;
    float bv[4]; int hh[4], dd[4];
    #pragma unroll
    for (int n = 0; n < 4; ++n) {
        int cg = colbase + n*16 + l15;
        bv[n] = bias[cg];
        int hd = cg & 1023;
        hh[n] = hd >> 6; dd[n] = hd & 63;
    }
    #pragma unroll
    for (int m = 0; m < 4; ++m) {
        int rowg = bm*128 + wr*64 + m*16 + lhi*4;
        #pragma unroll
        for (int j = 0; j < 4; ++j) {
            int rg = rowg + j;
            int b = rg >> 11, nseq = rg & 2047;
            #pragma unroll
            for (int n = 0; n < 4; ++n) {
                float val = acc[m][n][j] + bv[n];
                size_t bhn = (size_t)(b*NH + hh[n]);
                if (which == 0) {
                    qw[(bhn*SEQ + nseq)*HD + dd[n]] = f2bf(val * SCL);
                } else if (which == 1) {
                    kw[(bhn*SEQ + nseq)*HD + dd[n]] = f2bf(val);
                } else {
                    vtw[(bhn*HD + dd[n])*SEQ + nseq] = f2bf(val);
                }
            }
        }
    }
}

// ---------------- flash attention v8: cross-tile software pipeline ----------------
// 4 waves x 64 q-rows; 4 LDS buffers (static indices via explicit unroll),
// stage-ahead-3, counted vmcnt(4) (guarantees tile t+1 complete at iter t).
// Per iter t: STAGE(t+3) | QK(t+1)+exp -> pa/pb[next state] | PV(t) from
// pa/pb[current state]. PV(t) and QK(t+1) are fully independent -> post-barrier
// both streams issue immediately (no serial QK->SM->PV chain per tile).
// Swapped QK^T (K row-permuted at staging) keeps P lane-local; no-max softmax.
__global__ __launch_bounds__(256, 2) void attn_kernel(
        const u16* __restrict__ qw, const u16* __restrict__ kw,
        const u16* __restrict__ vtw, float* __restrict__ out)
{
    __shared__ u16 Ksh[4][64*64];
    __shared__ u16 Vsh[4][64*64];
    const int t = threadIdx.x;
    const int wave = t >> 6, lane = t & 63;
    const int l15 = lane & 15, lhi = lane >> 4;
    const int bh = blockIdx.x & 63;
    const int b = bh >> 4, h = bh & 15;
    const int q0 = (blockIdx.x >> 6) * 256 + wave * 64;

    const u16* Q  = qw  + (size_t)bh * SEQ * HD;
    const u16* Kg = kw  + (size_t)bh * SEQ * HD;
    const u16* Vg = vtw + (size_t)bh * HD * SEQ;

    const int srow = lane >> 3;
    const int scol = ((lane & 7) ^ srow) * 8;
    const int xorc = (l15 & 7) * 8;

    auto STAGE = [&](int buf, int kv) {
        #pragma unroll
        for (int half = 0; half < 2; ++half) {
            int crow = wave*16 + half*8 + srow;
            int kperm = (crow & 32) | ((crow & 12) << 1)
                      | ((crow & 16) >> 2) | (crow & 3);
            __builtin_amdgcn_global_load_lds(
                (const as1_u32*)(Kg + (size_t)(kv + kperm)*HD + scol),
                (as3_u32*)(&Ksh[buf][(wave*16 + half*8)*64]), 16, 0, 0);
            __builtin_amdgcn_global_load_lds(
                (const as1_u32*)(Vg + (size_t)crow*SEQ + kv + scol),
                (as3_u32*)(&Vsh[buf][(wave*16 + half*8)*64]), 16, 0, 0);
        }
    };

    // qf first (oldest in vmcnt), then 3 staged tiles.
    short8 qf[4][2];
    #pragma unroll
    for (int rf = 0; rf < 4; ++rf)
        #pragma unroll
        for (int ks = 0; ks < 2; ++ks)
            qf[rf][ks] = *(const short8*)(Q + (size_t)(q0 + rf*16 + l15)*HD + ks*32 + lhi*8);

    STAGE(0, 0);
    STAGE(1, 64);
    STAGE(2, 128);

    f32x4 o[4][4] = {};
    float lpart[4] = {0.f, 0.f, 0.f, 0.f};
    u32x4 paA[4], pbA[4], paB[4], pbB[4];

// QK(tile) from KBUF + exp -> (PA,PB) packed bf16 fragments, lane holds q=l15,
// k = 32(g>>1) + 8*lhi + 4(g&1) + j  (K row-permutation applied at staging).
#define QKSM(KBUF, PA, PB)                                                        \
    {                                                                             \
        _Pragma("unroll")                                                         \
        for (int g = 0; g < 4; ++g) {                                             \
            short8 kf0 = *(const short8*)(&(KBUF)[(g*16 + l15)*64 + ((lhi*8) ^ xorc)]);        \
            short8 kf1 = *(const short8*)(&(KBUF)[(g*16 + l15)*64 + ((32 + lhi*8) ^ xorc)]);   \
            f32x4 stg0 = {}, stg1 = {}, stg2 = {}, stg3 = {};                     \
            __builtin_amdgcn_s_setprio(1);                                        \
            stg0 = MFMA16(kf0, qf[0][0], stg0); stg1 = MFMA16(kf0, qf[1][0], stg1); \
            stg2 = MFMA16(kf0, qf[2][0], stg2); stg3 = MFMA16(kf0, qf[3][0], stg3); \
            stg0 = MFMA16(kf1, qf[0][1], stg0); stg1 = MFMA16(kf1, qf[1][1], stg1); \
            stg2 = MFMA16(kf1, qf[2][1], stg2); stg3 = MFMA16(kf1, qf[3][1], stg3); \
            __builtin_amdgcn_s_setprio(0);                                        \
            f32x4 stgs[4] = {stg0, stg1, stg2, stg3};                             \
            _Pragma("unroll")                                                     \
            for (int rf = 0; rf < 4; ++rf) {                                      \
                float p0 = __builtin_amdgcn_exp2f(stgs[rf][0]);                   \
                float p1 = __builtin_amdgcn_exp2f(stgs[rf][1]);                   \
                float p2 = __builtin_amdgcn_exp2f(stgs[rf][2]);                   \
                float p3 = __builtin_amdgcn_exp2f(stgs[rf][3]);                   \
                lpart[rf] += (p0 + p1) + (p2 + p3);                               \
                if (g < 2) {                                                      \
                    (PA)[rf][(g & 1)*2]     = pkbf2(p0, p1);                      \
                    (PA)[rf][(g & 1)*2 + 1] = pkbf2(p2, p3);                      \
                } else {                                                          \
                    (PB)[rf][(g & 1)*2]     = pkbf2(p0, p1);                      \
                    (PB)[rf][(g & 1)*2 + 1] = pkbf2(p2, p3);                      \
                }                                                                 \
            }                                                                     \
        }                                                                         \
    }

// PV from VBUF with packed fragments (PA,PB): o[rf][nd] += P @ V.
#define PVACC(VBUF, PA, PB)                                                       \
    {                                                                             \
        __builtin_amdgcn_s_setprio(1);                                            \
        _Pragma("unroll")                                                         \
        for (int ks = 0; ks < 2; ++ks)                                            \
            _Pragma("unroll")                                                     \
            for (int nd = 0; nd < 4; ++nd) {                                      \
                short8 vf = *(const short8*)(&(VBUF)[(nd*16 + l15)*64 + ((ks*32 + lhi*8) ^ xorc)]); \
                _Pragma("unroll")                                                 \
                for (int rf = 0; rf < 4; ++rf) {                                  \
                    short8 pfrag = __builtin_bit_cast(short8, ks == 0 ? (PA)[rf] : (PB)[rf]); \
                    o[rf][nd] = MFMA16(pfrag, vf, o[rf][nd]);                     \
                }                                                                 \
            }                                                                     \
        __builtin_amdgcn_s_setprio(0);                                            \
    }

// One pipelined iteration: tile T. BC = T&3 (PV buf), BN = (T+1)&3 (QK buf),
// BS = (T+3)&3 (stage buf). PAC/PBC = state for tile T, PAN/PBN for tile T+1.
#define BODY(T, BC, BN, BS, PAC, PBC, PAN, PBN)                                   \
    {                                                                             \
        asm volatile("s_waitcnt vmcnt(4)" ::: "memory");                          \
        __builtin_amdgcn_s_barrier();                                             \
        __builtin_amdgcn_sched_barrier(0);                                        \
        STAGE(BS, ((T) + 3 <= 31) ? ((T) + 3)*64 : 0);                            \
        QKSM(Ksh[BN], PAN, PBN);                                                  \
        PVACC(Vsh[BC], PAC, PBC);                                                 \
    }

    // prologue: tile 0 staged by all waves (own vmcnt covers own 12 stage loads
    // down to 8 = tiles 1,2 in flight; barrier publishes), then QK(0) -> state A.
    asm volatile("s_waitcnt vmcnt(8)" ::: "memory");
    __builtin_amdgcn_s_barrier();
    QKSM(Ksh[0], paA, pbA);

    for (int m = 0; m < 7; ++m) {
        int t0 = m * 4;
        BODY(t0 + 0, 0, 1, 3, paA, pbA, paB, pbB);
        BODY(t0 + 1, 1, 2, 0, paB, pbB, paA, pbA);
        BODY(t0 + 2, 2, 3, 1, paA, pbA, paB, pbB);
        BODY(t0 + 3, 3, 0, 2, paB, pbB, paA, pbA);
    }
    BODY(28, 0, 1, 3, paA, pbA, paB, pbB);
    BODY(29, 1, 2, 0, paB, pbB, paA, pbA);
    BODY(30, 2, 3, 1, paA, pbA, paB, pbB);
    // epilogue: PV(31); tile 31 publish guaranteed by t=30's vmcnt(4)+barrier.
    PVACC(Vsh[3], paB, pbB);

#undef BODY
#undef PVACC
#undef QKSM

    // L[q=l15] via butterfly over lhi groups; broadcast to lanes needing q=lhi*4+j.
    #pragma unroll
    for (int rf = 0; rf < 4; ++rf) {
        float l = lpart[rf];
        l += __shfl_xor(l, 16);
        l += __shfl_xor(l, 32);
        #pragma unroll
        for (int j = 0; j < 4; ++j) {
            float inv = 1.0f / __shfl(l, lhi*4 + j);
            int qrow = q0 + rf*16 + lhi*4 + j;
            float* orow = out + ((size_t)(b*SEQ + qrow))*CH + h*HD;
            #pragma unroll
            for (int nd = 0; nd < 4; ++nd)
                orow[nd*16 + l15] = o[rf][nd][j] * inv;
        }
    }
}

extern "C" void kernel_launch(void* const* d_in, const int* in_sizes, int n_in,
                              void* d_out, int out_size, void* d_ws, size_t ws_size,
                              hipStream_t stream) {
    const float* x    = (const float*)d_in[0];
    const float* w    = (const float*)d_in[1];
    const float* bias = (const float*)d_in[2];
    float* out = (float*)d_out;

    const size_t BHND = (size_t)NB*NH*SEQ*HD;   // 8388608
    u16* qw  = (u16*)d_ws;
    u16* kw  = qw  + BHND;
    u16* vtw = kw  + BHND;
    u16* xbf = vtw + BHND;
    u16* wbf = xbf + (size_t)M_TOT*K_TOT;

    const int nx8 = M_TOT*K_TOT/8;   // 1048576
    const int nw8 = N_TOT*K_TOT/8;   // 393216
    cvt_bf16_kernel<<<(nx8+nw8+255)/256, 256, 0, stream>>>(x, xbf, nx8, w, wbf, nw8);
    qkv_gemm_kernel<<<(M_TOT/128)*(N_TOT/128), 256, 0, stream>>>(xbf, wbf, bias, qw, kw, vtw);
    attn_kernel<<<(SEQ/256)*NB*NH, 256, 0, stream>>>(qw, kw, vtw, out);
}

// Round 10
// 180.572 us; speedup vs baseline: 1.0823x; 1.0823x over previous
//
#include <hip/hip_runtime.h>
#include <hip/hip_bf16.h>

typedef __attribute__((ext_vector_type(8))) short short8;
typedef __attribute__((ext_vector_type(4))) float f32x4;
typedef __attribute__((ext_vector_type(4))) unsigned int u32x4;
typedef unsigned short u16;
typedef unsigned int u32;

typedef u32 __attribute__((address_space(1))) as1_u32;
typedef u32 __attribute__((address_space(3))) as3_u32;

#define NB 4
#define SEQ 2048
#define CH 1024
#define NH 16
#define HD 64
#define M_TOT (NB*SEQ)   // 8192
#define N_TOT (3*CH)     // 3072
#define K_TOT CH         // 1024
#define SCL 0.18033688f  // log2(e) / sqrt(64)

#define MFMA16(a,b,c) __builtin_amdgcn_mfma_f32_16x16x32_bf16((a),(b),(c),0,0,0)

__device__ __forceinline__ u16 f2bf(float f) {
    union { float f; u32 u; } v; v.f = f;
    u32 u = v.u;
    return (u16)((u + 0x7fffu + ((u >> 16) & 1u)) >> 16);
}

__device__ __forceinline__ u32 pkbf2(float a, float b) {
    union { __hip_bfloat162 h; u32 u; } x;
    x.h = __float22bfloat162_rn(float2{a, b});
    return x.u;   // low 16 bits = a, high = b
}

// ---------------- fp32 -> bf16 conversion (x and w in one launch) ----------------
__global__ void cvt_bf16_kernel(const float* __restrict__ x, u16* __restrict__ xb, int nx8,
                                const float* __restrict__ w, u16* __restrict__ wb, int nw8) {
    int i = blockIdx.x * 256 + threadIdx.x;
    const float* src; u16* dst; int idx;
    if (i < nx8) { src = x; dst = xb; idx = i; }
    else { idx = i - nx8; if (idx >= nw8) return; src = w; dst = wb; }
    const float4* s4 = (const float4*)src;
    float4 a = s4[2*idx], b = s4[2*idx+1];
    u32x4 r;
    r[0] = pkbf2(a.x, a.y); r[1] = pkbf2(a.z, a.w);
    r[2] = pkbf2(b.x, b.y); r[3] = pkbf2(b.z, b.w);
    *(u32x4*)(dst + (size_t)idx*8) = r;
}

// ---------------- QKV projection GEMM (R7 version, ~880 TF) ----------------
__global__ __launch_bounds__(256) void qkv_gemm_kernel(
        const u16* __restrict__ A, const u16* __restrict__ W,
        const float* __restrict__ bias,
        u16* __restrict__ qw, u16* __restrict__ kw, u16* __restrict__ vtw)
{
    __shared__ u16 As[128*32];
    __shared__ u16 Bs[128*32];
    const int t = threadIdx.x;
    const int wave = t >> 6;
    const int lane = t & 63;
    const int l15 = lane & 15, lhi = lane >> 4;
    const int wr = wave >> 1, wc = wave & 1;
    const int xcd = blockIdx.x & 7;
    const int idx = blockIdx.x >> 3;
    const int bm = xcd * 8 + (idx & 7);
    const int bn = idx >> 3;

    f32x4 acc[4][4] = {};

    const int arow = t >> 2;
    const int acol = (t & 3) * 8;
    const u16* gA = A + (size_t)(bm*128 + arow)*K_TOT + acol;
    const u16* gB = W + (size_t)(bn*128 + arow)*K_TOT + acol;

    for (int k0 = 0; k0 < K_TOT; k0 += 32) {
        #pragma unroll
        for (int i = 0; i < 2; ++i) {
            __builtin_amdgcn_global_load_lds(
                (const as1_u32*)(gA + (size_t)i*64*K_TOT + k0),
                (as3_u32*)(As + i*2048 + wave*512), 16, 0, 0);
            __builtin_amdgcn_global_load_lds(
                (const as1_u32*)(gB + (size_t)i*64*K_TOT + k0),
                (as3_u32*)(Bs + i*2048 + wave*512), 16, 0, 0);
        }
        __syncthreads();
        short8 af[4], bfr[4];
        #pragma unroll
        for (int m = 0; m < 4; ++m)
            af[m] = *(const short8*)(As + (wr*64 + m*16 + l15)*32 + lhi*8);
        #pragma unroll
        for (int n = 0; n < 4; ++n)
            bfr[n] = *(const short8*)(Bs + (wc*64 + n*16 + l15)*32 + lhi*8);
        #pragma unroll
        for (int m = 0; m < 4; ++m)
            #pragma unroll
            for (int n = 0; n < 4; ++n)
                acc[m][n] = MFMA16(af[m], bfr[n], acc[m][n]);
        __syncthreads();
    }

    const int colbase = bn*128 + wc*64;
    const int which = colbase >> 10;
    float bv[4]; int hh[4], dd[4];
    #pragma unroll
    for (int n = 0; n < 4; ++n) {
        int cg = colbase + n*16 + l15;
        bv[n] = bias[cg];
        int hd = cg & 1023;
        hh[n] = hd >> 6; dd[n] = hd & 63;
    }
    #pragma unroll
    for (int m = 0; m < 4; ++m) {
        int rowg = bm*128 + wr*64 + m*16 + lhi*4;
        #pragma unroll
        for (int j = 0; j < 4; ++j) {
            int rg = rowg + j;
            int b = rg >> 11, nseq = rg & 2047;
            #pragma unroll
            for (int n = 0; n < 4; ++n) {
                float val = acc[m][n][j] + bv[n];
                size_t bhn = (size_t)(b*NH + hh[n]);
                if (which == 0) {
                    qw[(bhn*SEQ + nseq)*HD + dd[n]] = f2bf(val * SCL);
                } else if (which == 1) {
                    kw[(bhn*SEQ + nseq)*HD + dd[n]] = f2bf(val);
                } else {
                    vtw[(bhn*HD + dd[n])*SEQ + nseq] = f2bf(val);
                }
            }
        }
    }
}

// ---------------- flash attention v9: cross-tile pipeline, rf=2 (no spills) ----------------
// 8 waves x 32 q-rows; 4 LDS buffers, stage-ahead-3 (2 loads/wave/stage), counted
// vmcnt(2) in-loop. Per iter t: STAGE(t+3) | QK(t+1)+exp -> next P-state | PV(t)
// from current P-state. PV(t) and QK(t+1) are independent -> both streams issue
// right after the barrier. All buffer/state indices static (explicit x4 unroll,
// named A/B state sets). Swapped QK^T (K row-permuted at staging) keeps P
// lane-local; no-max softmax (Q pre-scaled by log2e/sqrt(D)).
__global__ __launch_bounds__(512, 2) void attn_kernel(
        const u16* __restrict__ qw, const u16* __restrict__ kw,
        const u16* __restrict__ vtw, float* __restrict__ out)
{
    __shared__ u16 Ksh[4][64*64];
    __shared__ u16 Vsh[4][64*64];
    const int t = threadIdx.x;
    const int wave = t >> 6, lane = t & 63;
    const int l15 = lane & 15, lhi = lane >> 4;
    const int bh = blockIdx.x & 63;
    const int b = bh >> 4, h = bh & 15;
    const int q0 = (blockIdx.x >> 6) * 256 + wave * 32;

    const u16* Q  = qw  + (size_t)bh * SEQ * HD;
    const u16* Kg = kw  + (size_t)bh * SEQ * HD;
    const u16* Vg = vtw + (size_t)bh * HD * SEQ;

    // staging: wave w owns LDS rows 8w..8w+7; dest linear, source col pre-swizzled,
    // K source row permuted (pos=32a+16b+4c+d holds logical k=32a+8c+4b+d).
    const int srow = lane >> 3;
    const int scol = ((lane & 7) ^ srow) * 8;
    const int crow = wave * 8 + srow;
    const int kperm = (crow & 32) | ((crow & 12) << 1)
                    | ((crow & 16) >> 2) | (crow & 3);
    const int xorc = (l15 & 7) * 8;

    auto STAGE = [&](int buf, int kv) {
        __builtin_amdgcn_global_load_lds(
            (const as1_u32*)(Kg + (size_t)(kv + kperm)*HD + scol),
            (as3_u32*)(&Ksh[buf][wave*8*64]), 16, 0, 0);
        __builtin_amdgcn_global_load_lds(
            (const as1_u32*)(Vg + (size_t)crow*SEQ + kv + scol),
            (as3_u32*)(&Vsh[buf][wave*8*64]), 16, 0, 0);
    };

    // qf first (oldest in vmcnt), then 3 staged tiles.
    short8 qf[2][2];
    #pragma unroll
    for (int rf = 0; rf < 2; ++rf)
        #pragma unroll
        for (int ks = 0; ks < 2; ++ks)
            qf[rf][ks] = *(const short8*)(Q + (size_t)(q0 + rf*16 + l15)*HD + ks*32 + lhi*8);

    STAGE(0, 0);
    STAGE(1, 64);
    STAGE(2, 128);

    f32x4 o[2][4] = {};
    float lpart[2] = {0.f, 0.f};
    u32x4 paA[2], pbA[2], paB[2], pbB[2];

// QK(tile) from KBUF + exp -> (PA,PB) packed bf16 fragments; lane holds q=l15,
// k = 32(g>>1) + 8*lhi + 4(g&1) + j  (K row-permutation applied at staging).
#define QKSM(KBUF, PA, PB)                                                        \
    {                                                                             \
        _Pragma("unroll")                                                         \
        for (int g = 0; g < 4; ++g) {                                             \
            short8 kf0 = *(const short8*)(&(KBUF)[(g*16 + l15)*64 + ((lhi*8) ^ xorc)]);      \
            short8 kf1 = *(const short8*)(&(KBUF)[(g*16 + l15)*64 + ((32 + lhi*8) ^ xorc)]); \
            f32x4 s0 = {}, s1 = {};                                               \
            __builtin_amdgcn_s_setprio(1);                                        \
            s0 = MFMA16(kf0, qf[0][0], s0);                                       \
            s1 = MFMA16(kf0, qf[1][0], s1);                                       \
            s0 = MFMA16(kf1, qf[0][1], s0);                                       \
            s1 = MFMA16(kf1, qf[1][1], s1);                                       \
            __builtin_amdgcn_s_setprio(0);                                        \
            {                                                                     \
                float p0 = __builtin_amdgcn_exp2f(s0[0]);                         \
                float p1 = __builtin_amdgcn_exp2f(s0[1]);                         \
                float p2 = __builtin_amdgcn_exp2f(s0[2]);                         \
                float p3 = __builtin_amdgcn_exp2f(s0[3]);                         \
                lpart[0] += (p0 + p1) + (p2 + p3);                                \
                if (g < 2) { (PA)[0][(g&1)*2] = pkbf2(p0,p1); (PA)[0][(g&1)*2+1] = pkbf2(p2,p3); } \
                else       { (PB)[0][(g&1)*2] = pkbf2(p0,p1); (PB)[0][(g&1)*2+1] = pkbf2(p2,p3); } \
            }                                                                     \
            {                                                                     \
                float p0 = __builtin_amdgcn_exp2f(s1[0]);                         \
                float p1 = __builtin_amdgcn_exp2f(s1[1]);                         \
                float p2 = __builtin_amdgcn_exp2f(s1[2]);                         \
                float p3 = __builtin_amdgcn_exp2f(s1[3]);                         \
                lpart[1] += (p0 + p1) + (p2 + p3);                                \
                if (g < 2) { (PA)[1][(g&1)*2] = pkbf2(p0,p1); (PA)[1][(g&1)*2+1] = pkbf2(p2,p3); } \
                else       { (PB)[1][(g&1)*2] = pkbf2(p0,p1); (PB)[1][(g&1)*2+1] = pkbf2(p2,p3); } \
            }                                                                     \
        }                                                                         \
    }

// PV from VBUF with packed fragments (PA,PB): o[rf][nd] += P @ V.
#define PVACC(VBUF, PA, PB)                                                       \
    {                                                                             \
        __builtin_amdgcn_s_setprio(1);                                            \
        _Pragma("unroll")                                                         \
        for (int ks = 0; ks < 2; ++ks)                                            \
            _Pragma("unroll")                                                     \
            for (int nd = 0; nd < 4; ++nd) {                                      \
                short8 vf = *(const short8*)(&(VBUF)[(nd*16 + l15)*64 + ((ks*32 + lhi*8) ^ xorc)]); \
                o[0][nd] = MFMA16(__builtin_bit_cast(short8, ks == 0 ? (PA)[0] : (PB)[0]), vf, o[0][nd]); \
                o[1][nd] = MFMA16(__builtin_bit_cast(short8, ks == 0 ? (PA)[1] : (PB)[1]), vf, o[1][nd]); \
            }                                                                     \
        __builtin_amdgcn_s_setprio(0);                                            \
    }

// One pipelined iteration: tile T. BC = T&3 (PV buf), BN = (T+1)&3 (QK buf),
// BS = (T+3)&3 (stage buf). PAC/PBC = P-state for tile T, PAN/PBN for tile T+1.
#define BODY(T, BC, BN, BS, PAC, PBC, PAN, PBN)                                   \
    {                                                                             \
        asm volatile("s_waitcnt vmcnt(2)" ::: "memory");                          \
        __builtin_amdgcn_s_barrier();                                             \
        __builtin_amdgcn_sched_barrier(0);                                        \
        STAGE(BS, ((T) + 3 <= 31) ? ((T) + 3)*64 : 0);                            \
        QKSM(Ksh[BN], PAN, PBN);                                                  \
        PVACC(Vsh[BC], PAC, PBC);                                                 \
    }

    // prologue: wait qf(4)+tile0(2) (leaves tiles 1,2 = 4 in flight), publish,
    // then QK(0) -> state A.
    asm volatile("s_waitcnt vmcnt(4)" ::: "memory");
    __builtin_amdgcn_s_barrier();
    QKSM(Ksh[0], paA, pbA);

    for (int m = 0; m < 7; ++m) {
        int t0 = m * 4;
        (void)t0;
        BODY(t0 + 0, 0, 1, 3, paA, pbA, paB, pbB);
        BODY(t0 + 1, 1, 2, 0, paB, pbB, paA, pbA);
        BODY(t0 + 2, 2, 3, 1, paA, pbA, paB, pbB);
        BODY(t0 + 3, 3, 0, 2, paB, pbB, paA, pbA);
    }
    BODY(28, 0, 1, 3, paA, pbA, paB, pbB);
    BODY(29, 1, 2, 0, paB, pbB, paA, pbA);
    BODY(30, 2, 3, 1, paA, pbA, paB, pbB);
    // epilogue: PV(31); tile 31 completion guaranteed by t=30's vmcnt(2)+barrier.
    PVACC(Vsh[3], paB, pbB);

#undef BODY
#undef PVACC
#undef QKSM

    // L[q=l15] via butterfly over lhi groups; broadcast to lanes needing q=lhi*4+j.
    #pragma unroll
    for (int rf = 0; rf < 2; ++rf) {
        float l = lpart[rf];
        l += __shfl_xor(l, 16);
        l += __shfl_xor(l, 32);
        #pragma unroll
        for (int j = 0; j < 4; ++j) {
            float inv = 1.0f / __shfl(l, lhi*4 + j);
            int qrow = q0 + rf*16 + lhi*4 + j;
            float* orow = out + ((size_t)(b*SEQ + qrow))*CH + h*HD;
            #pragma unroll
            for (int nd = 0; nd < 4; ++nd)
                orow[nd*16 + l15] = o[rf][nd][j] * inv;
        }
    }
}

extern "C" void kernel_launch(void* const* d_in, const int* in_sizes, int n_in,
                              void* d_out, int out_size, void* d_ws, size_t ws_size,
                              hipStream_t stream) {
    const float* x    = (const float*)d_in[0];
    const float* w    = (const float*)d_in[1];
    const float* bias = (const float*)d_in[2];
    float* out = (float*)d_out;

    const size_t BHND = (size_t)NB*NH*SEQ*HD;   // 8388608
    u16* qw  = (u16*)d_ws;
    u16* kw  = qw  + BHND;
    u16* vtw = kw  + BHND;
    u16* xbf = vtw + BHND;
    u16* wbf = xbf + (size_t)M_TOT*K_TOT;

    const int nx8 = M_TOT*K_TOT/8;   // 1048576
    const int nw8 = N_TOT*K_TOT/8;   // 393216
    cvt_bf16_kernel<<<(nx8+nw8+255)/256, 256, 0, stream>>>(x, xbf, nx8, w, wbf, nw8);
    qkv_gemm_kernel<<<(M_TOT/128)*(N_TOT/128), 256, 0, stream>>>(xbf, wbf, bias, qw, kw, vtw);
    attn_kernel<<<(SEQ/256)*NB*NH, 512, 0, stream>>>(qw, kw, vtw, out);
}